// Round 6
// baseline (426.569 us; speedup 1.0000x reference)
//
#include <hip/hip_runtime.h>
#include <cstdint>

typedef unsigned short u16;
typedef __bf16 bf16x8 __attribute__((ext_vector_type(8)));
typedef float f32x4 __attribute__((ext_vector_type(4)));
typedef unsigned short u16x8 __attribute__((ext_vector_type(8)));
typedef unsigned short u16x4 __attribute__((ext_vector_type(4)));

// ---------- helpers ----------
__device__ __forceinline__ u16 f2b(float f) {  // fp32 -> bf16 RNE
  union { float f; unsigned u; } x; x.f = f;
  unsigned r = (x.u + 0x7FFFu + ((x.u >> 16) & 1u)) >> 16;
  return (u16)r;
}
__device__ __forceinline__ float b2f(u16 v) {
  union { unsigned u; float f; } x; x.u = (unsigned)v << 16; return x.f;
}

__device__ __forceinline__ void gload_lds16(const void* g, void* l) {
  __builtin_amdgcn_global_load_lds(
      (__attribute__((address_space(1))) void*)(uintptr_t)g,
      (__attribute__((address_space(3))) void*)(uintptr_t)l, 16, 0, 0);
}

// ---------- fp32 -> bf16 cast ----------
__global__ void cast_kernel(const float* __restrict__ in, u16* __restrict__ out, int n4) {
  int i = blockIdx.x * 256 + threadIdx.x;
  if (i < n4) {
    float4 v = *(const float4*)(in + (size_t)i * 4);
    u16x4 o = {f2b(v.x), f2b(v.y), f2b(v.z), f2b(v.w)};
    *(u16x4*)(out + (size_t)i * 4) = o;
  }
}

// ---------- bias arrange: per-lane register order ----------
// out[((h*64+qt)*4+w)*4096 + (w_lane)*64 + nt*4 + j]
//   = bf16(bias[h][qt*16 + (lane>>4)*4 + j][w*256 + nt*16 + (lane&15)])
// One block per (h,qt) slice: coalesced fp32 read -> LDS -> gathered write.
__global__ void bias_arrange_kernel(const float* __restrict__ in, u16* __restrict__ out) {
  const int hq = blockIdx.x;           // h*64 + qt
  const int tid = threadIdx.x;
  __shared__ u16 t16[16 * 1032];       // +8 pad per row
  const float* src = in + (size_t)hq * 16 * 1024;
#pragma unroll
  for (int i = 0; i < 16; ++i) {
    const float4 v = *(const float4*)(src + (size_t)i * 1024 + tid * 4);
    u16x4 o = {f2b(v.x), f2b(v.y), f2b(v.z), f2b(v.w)};
    *(u16x4*)&t16[i * 1032 + tid * 4] = o;
  }
  __syncthreads();
  u16* obase = out + (size_t)hq * 16384;
  const int w = tid >> 6, lane = tid & 63;
  const int g = lane >> 4, r = lane & 15;
#pragma unroll
  for (int k = 0; k < 8; ++k) {        // chunk covers nt = 2k, 2k+1
    u16x8 o;
#pragma unroll
    for (int t = 0; t < 2; ++t) {
      const int nt = k * 2 + t;
#pragma unroll
      for (int j = 0; j < 4; ++j)
        o[t * 4 + j] = t16[(g * 4 + j) * 1032 + w * 256 + nt * 16 + r];
    }
    *(u16x8*)(obase + tid * 64 + k * 8) = o;
  }
}

// ---------- GEMM: C[M,N] = A[M,K] * B[N,K]^T (+bias, +gelu, +resid) ----------
template<bool GELU_ACT>
__global__ void gemm_nt(const u16* __restrict__ A, const u16* __restrict__ Bw,
                        const float* __restrict__ bias, const float* __restrict__ resid,
                        float* __restrict__ Cf, u16* __restrict__ Cb,
                        int M, int N, int K) {
  __shared__ u16 As[2][128 * 32];
  __shared__ u16 Bs[2][128 * 32];
  const int tid = threadIdx.x;
  const int lane = tid & 63, wid = tid >> 6;
  const int bm = blockIdx.y * 128, bn = blockIdx.x * 128;
  const int wm = wid >> 1, wn = wid & 1;
  const int r = lane & 15, g = lane >> 4;

  auto stage = [&](int buf, int k0) {
#pragma unroll
    for (int i = 0; i < 2; ++i) {
      int c = tid + i * 256;
      const u16* ga = A + (size_t)(bm + (c >> 2)) * K + k0 + (c & 3) * 8;
      const u16* gb = Bw + (size_t)(bn + (c >> 2)) * K + k0 + (c & 3) * 8;
      gload_lds16(ga, &As[buf][c * 8]);
      gload_lds16(gb, &Bs[buf][c * 8]);
    }
  };

  f32x4 acc[4][4] = {};
  stage(0, 0);
  __syncthreads();
  const int nk = K >> 5;
  int cur = 0;
  for (int kt = 0; kt < nk; ++kt) {
    if (kt + 1 < nk) stage(cur ^ 1, (kt + 1) * 32);
    bf16x8 af[4], bfr[4];
#pragma unroll
    for (int m = 0; m < 4; ++m)
      af[m] = *(const bf16x8*)&As[cur][(wm * 64 + m * 16 + r) * 32 + g * 8];
#pragma unroll
    for (int n = 0; n < 4; ++n)
      bfr[n] = *(const bf16x8*)&Bs[cur][(wn * 64 + n * 16 + r) * 32 + g * 8];
#pragma unroll
    for (int m = 0; m < 4; ++m)
#pragma unroll
      for (int n = 0; n < 4; ++n)
        acc[m][n] = __builtin_amdgcn_mfma_f32_16x16x32_bf16(af[m], bfr[n], acc[m][n], 0, 0, 0);
    __syncthreads();
    cur ^= 1;
  }
#pragma unroll
  for (int m = 0; m < 4; ++m) {
    const int row0 = bm + wm * 64 + m * 16 + g * 4;
#pragma unroll
    for (int n = 0; n < 4; ++n) {
      const int col = bn + wn * 64 + n * 16 + r;
      const float bv = bias ? bias[col] : 0.f;
#pragma unroll
      for (int j = 0; j < 4; ++j) {
        float v = acc[m][n][j] + bv;
        if (GELU_ACT) v = 0.5f * v * (1.f + erff(v * 0.70710678118654752f));
        const size_t idx = (size_t)(row0 + j) * N + col;
        if (resid) v += resid[idx];
        if (Cf) Cf[idx] = v;
        if (Cb) Cb[idx] = f2b(v);
      }
    }
  }
}

// ---------- V transpose: qkv[4096,3072] -> Vt[64 bh][64 d][1024 s] ----------
__global__ void vtrans_kernel(const u16* __restrict__ qkv, u16* __restrict__ Vt) {
  const int bh = blockIdx.y, b = bh >> 4, h = bh & 15;
  const int s0 = blockIdx.x * 128;
  const int tid = threadIdx.x;
  __shared__ u16 t[128][66];
#pragma unroll
  for (int i = 0; i < 32; ++i) {
    const int e = tid + i * 256;
    const int s = e >> 6, d = e & 63;
    t[s][d] = qkv[(size_t)(b * 1024 + s0 + s) * 3072 + 2048 + h * 64 + d];
  }
  __syncthreads();
#pragma unroll
  for (int i = 0; i < 4; ++i) {
    const int c = tid + i * 256;
    const int d = c >> 4, scol = (c & 15) * 8;
    u16x8 v;
#pragma unroll
    for (int j = 0; j < 8; ++j) v[j] = t[scol + j][d];
    *(u16x8*)(Vt + ((size_t)bh * 64 + d) * 1024 + s0 + scol) = v;
  }
}

// ---------- fused attention v6 ----------
// Scores never touch LDS as f32: pass A keeps them packed bf16 in registers
// (32 VGPRs, statically indexed). Bias comes pre-arranged per-lane from
// global (vector loads). One LDS pass: exp sweep writes unnormalized P;
// 1/l folds into the PV epilogue. Two barriers. PV uses 2 accumulators.
__global__ __launch_bounds__(256, 4) void attn_kernel(
    const u16* __restrict__ qkv, const u16* __restrict__ Vt,
    const u16* __restrict__ biasa, u16* __restrict__ ctx) {
  const int yy = blockIdx.y;           // h*4 + b
  const int h = yy >> 2, b = yy & 3;
  const int qt = blockIdx.x;
  const int q0 = qt * 16;
  const int tid = threadIdx.x;
  const int lane = tid & 63, wid = tid >> 6;
  const int r = lane & 15, g = lane >> 4;
  const int bh = b * 16 + h;

  __shared__ __align__(16) u16 PB[16 * 1024];
  __shared__ float redmax[4][16], redsum[4][16];

  // Q fragments: row = lane&15 (q-row), k = g*8..
  const size_t qbase = (size_t)(b * 1024 + q0 + r) * 3072 + h * 64;
  const bf16x8 aq0 = *(const bf16x8*)(qkv + qbase + g * 8);
  const bf16x8 aq1 = *(const bf16x8*)(qkv + qbase + 32 + g * 8);

  // pre-arranged bias: 64 contiguous bf16 per lane
  const u16* bptr = biasa + (((size_t)(h * 64 + qt) * 4 + wid) * 64 + lane) * 64;

  const int n0 = wid * 256;            // this wave's 256 key columns
  u16x8 sp[8];                         // packed bf16 scores [np], elem t*4+j
  float mj[4] = {-3.0e38f, -3.0e38f, -3.0e38f, -3.0e38f};

  // pass A: QK^T + arranged bias, scores -> packed regs, track row max
#pragma unroll
  for (int np = 0; np < 8; ++np) {
    const bf16x8 bias8 = *(const bf16x8*)(bptr + np * 8);
    u16x8 o8;
#pragma unroll
    for (int t = 0; t < 2; ++t) {
      const int nt = np * 2 + t;
      const int scol = n0 + nt * 16 + r;
      const size_t kbase = (size_t)(b * 1024 + scol) * 3072 + 1024 + h * 64;
      const bf16x8 bk0 = *(const bf16x8*)(qkv + kbase + g * 8);
      const bf16x8 bk1 = *(const bf16x8*)(qkv + kbase + 32 + g * 8);
      f32x4 a = {0.f, 0.f, 0.f, 0.f};
      a = __builtin_amdgcn_mfma_f32_16x16x32_bf16(aq0, bk0, a, 0, 0, 0);
      a = __builtin_amdgcn_mfma_f32_16x16x32_bf16(aq1, bk1, a, 0, 0, 0);
#pragma unroll
      for (int j = 0; j < 4; ++j) {
        const float s = fmaf(a[j], 0.125f, b2f((u16)bias8[t * 4 + j]));
        mj[j] = fmaxf(mj[j], s);
        o8[t * 4 + j] = f2b(s);
      }
    }
    sp[np] = o8;
  }
  // row max: across 16 col-lanes, then across 4 waves
#pragma unroll
  for (int j = 0; j < 4; ++j) {
    float v = mj[j];
    v = fmaxf(v, __shfl_xor(v, 1)); v = fmaxf(v, __shfl_xor(v, 2));
    v = fmaxf(v, __shfl_xor(v, 4)); v = fmaxf(v, __shfl_xor(v, 8));
    if (r == 0) redmax[wid][g * 4 + j] = v;
  }
  __syncthreads();
#pragma unroll
  for (int j = 0; j < 4; ++j)
    mj[j] = fmaxf(fmaxf(redmax[0][g * 4 + j], redmax[1][g * 4 + j]),
                  fmaxf(redmax[2][g * 4 + j], redmax[3][g * 4 + j]));

  // exp sweep: p = exp(s-m); write unnormalized bf16 P to LDS; accumulate l
  float l[4] = {0.f, 0.f, 0.f, 0.f};
#pragma unroll
  for (int np = 0; np < 8; ++np) {
    const u16x8 v = sp[np];
#pragma unroll
    for (int t = 0; t < 2; ++t) {
      const int nt = np * 2 + t;
#pragma unroll
      for (int j = 0; j < 4; ++j) {
        const float p = __expf(b2f((u16)v[t * 4 + j]) - mj[j]);
        l[j] += p;
        const int row = g * 4 + j;
        const int col = n0 + nt * 16 + r;
        PB[row * 1024 + (col ^ ((row & 15) << 3))] = f2b(p);
      }
    }
  }
#pragma unroll
  for (int j = 0; j < 4; ++j) {
    float s = l[j];
    s += __shfl_xor(s, 1); s += __shfl_xor(s, 2);
    s += __shfl_xor(s, 4); s += __shfl_xor(s, 8);
    if (r == 0) redsum[wid][g * 4 + j] = s;
  }
  __syncthreads();                     // redsum AND all P writes visible

  float inv[4];
#pragma unroll
  for (int j = 0; j < 4; ++j)
    inv[j] = 1.f / (redsum[0][g * 4 + j] + redsum[1][g * 4 + j] +
                    redsum[2][g * 4 + j] + redsum[3][g * 4 + j]);

  // PV: wave wid owns d-tile [wid*16, wid*16+16); two independent chains
  f32x4 oa = {0.f, 0.f, 0.f, 0.f}, ob = {0.f, 0.f, 0.f, 0.f};
  const u16* vrow = Vt + ((size_t)bh * 64 + wid * 16 + r) * 1024;
#pragma unroll 4
  for (int ks = 0; ks < 32; ks += 2) {
    const bf16x8 pa0 = *(const bf16x8*)&PB[r * 1024 + ((ks * 32 + g * 8) ^ ((r & 15) << 3))];
    const bf16x8 vb0 = *(const bf16x8*)(vrow + ks * 32 + g * 8);
    oa = __builtin_amdgcn_mfma_f32_16x16x32_bf16(pa0, vb0, oa, 0, 0, 0);
    const bf16x8 pa1 = *(const bf16x8*)&PB[r * 1024 + (((ks + 1) * 32 + g * 8) ^ ((r & 15) << 3))];
    const bf16x8 vb1 = *(const bf16x8*)(vrow + (ks + 1) * 32 + g * 8);
    ob = __builtin_amdgcn_mfma_f32_16x16x32_bf16(pa1, vb1, ob, 0, 0, 0);
  }
#pragma unroll
  for (int j = 0; j < 4; ++j)
    ctx[(size_t)(b * 1024 + q0 + g * 4 + j) * 1024 + h * 64 + wid * 16 + r] =
        f2b((oa[j] + ob[j]) * inv[j]);
}

// ---------- LayerNorm over D=1024, one block per row ----------
__global__ void ln_kernel(const float* __restrict__ x, const float* __restrict__ gw,
                          const float* __restrict__ bw, float* __restrict__ outf,
                          u16* __restrict__ outb) {
  const int row = blockIdx.x, tid = threadIdx.x;
  const float4 v = *(const float4*)(x + (size_t)row * 1024 + tid * 4);
  float s = v.x + v.y + v.z + v.w;
  float q = v.x * v.x + v.y * v.y + v.z * v.z + v.w * v.w;
#pragma unroll
  for (int m = 32; m >= 1; m >>= 1) { s += __shfl_xor(s, m); q += __shfl_xor(q, m); }
  __shared__ float rs[4], rq[4];
  if ((tid & 63) == 0) { rs[tid >> 6] = s; rq[tid >> 6] = q; }
  __syncthreads();
  s = rs[0] + rs[1] + rs[2] + rs[3];
  q = rq[0] + rq[1] + rq[2] + rq[3];
  const float mu = s * (1.f / 1024.f);
  const float inv = rsqrtf(q * (1.f / 1024.f) - mu * mu + 1e-5f);
  const float4 g4 = *(const float4*)(gw + tid * 4);
  const float4 b4 = *(const float4*)(bw + tid * 4);
  float4 o;
  o.x = (v.x - mu) * inv * g4.x + b4.x;
  o.y = (v.y - mu) * inv * g4.y + b4.y;
  o.z = (v.z - mu) * inv * g4.z + b4.z;
  o.w = (v.w - mu) * inv * g4.w + b4.w;
  if (outf) *(float4*)(outf + (size_t)row * 1024 + tid * 4) = o;
  if (outb) {
    u16x4 ob = {f2b(o.x), f2b(o.y), f2b(o.z), f2b(o.w)};
    *(u16x4*)(outb + (size_t)row * 1024 + tid * 4) = ob;
  }
}

// ---------- launch ----------
extern "C" void kernel_launch(void* const* d_in, const int* in_sizes, int n_in,
                              void* d_out, int out_size, void* d_ws, size_t ws_size,
                              hipStream_t stream) {
  (void)in_sizes; (void)n_in; (void)out_size; (void)ws_size;
  const float* src   = (const float*)d_in[0];
  const float* abias = (const float*)d_in[1];
  const float* Wqkv  = (const float*)d_in[2];
  const float* bqkv  = (const float*)d_in[3];
  const float* Wo    = (const float*)d_in[4];
  const float* bo    = (const float*)d_in[5];
  const float* g1    = (const float*)d_in[6];
  const float* b1n   = (const float*)d_in[7];
  const float* g2    = (const float*)d_in[8];
  const float* b2n   = (const float*)d_in[9];
  const float* W1    = (const float*)d_in[10];
  const float* b1    = (const float*)d_in[11];
  const float* W2    = (const float*)d_in[12];
  const float* b2    = (const float*)d_in[13];
  float* out = (float*)d_out;

  char* ws = (char*)d_ws;
  const size_t MB = 1024 * 1024;
  // lifetime-aliased layout, 104 MB total
  u16* srcb  = (u16*)(ws + 0 * MB);     // dead after gemm1
  u16* ctxb  = (u16*)(ws + 0 * MB);     // alias of srcb (written by attn)
  u16* Wqkvb = (u16*)(ws + 8 * MB);
  u16* Wob   = (u16*)(ws + 14 * MB);
  u16* W1b   = (u16*)(ws + 16 * MB);
  u16* W2b   = (u16*)(ws + 24 * MB);
  u16* qkvb  = (u16*)(ws + 32 * MB);    // 24 MB; dead after attn
  u16* hb    = (u16*)(ws + 32 * MB);    // alias (32 MB, written by gemm3)
  u16* Vt    = (u16*)(ws + 56 * MB);    // 8 MB; dead after attn
  u16* biasa = (u16*)(ws + 64 * MB);    // 32 MB (64..96); dead after attn
  float* sum1 = (float*)(ws + 64 * MB); // 16 MB (after attn); dead after ln1
  float* yf   = (float*)(ws + 64 * MB); // alias (written by gemm4)
  float* xf   = (float*)(ws + 80 * MB); // written by ln1 (after attn)
  u16* xb    = (u16*)(ws + 96 * MB);

  auto cast = [&](const float* in, u16* o, int n) {
    cast_kernel<<<(n / 4 + 255) / 256, 256, 0, stream>>>(in, o, n / 4);
  };
  cast(src, srcb, 4096 * 1024);
  cast(Wqkv, Wqkvb, 3072 * 1024);
  cast(Wo, Wob, 1024 * 1024);
  cast(W1, W1b, 4096 * 1024);
  cast(W2, W2b, 1024 * 4096);
  // bias: fp32 -> bf16 arranged per (h,qtile,wave,lane)
  bias_arrange_kernel<<<16 * 64, 256, 0, stream>>>(abias, biasa);

  // qkv = src @ Wqkv^T + bqkv  -> bf16 [4096, 3072]
  gemm_nt<false><<<dim3(3072 / 128, 4096 / 128), 256, 0, stream>>>(
      srcb, Wqkvb, bqkv, nullptr, nullptr, qkvb, 4096, 3072, 1024);
  // Vt[bh][d][s]
  vtrans_kernel<<<dim3(8, 64), 256, 0, stream>>>(qkvb, Vt);
  // attention -> ctx bf16 [4096, 1024]
  attn_kernel<<<dim3(64, 64), 256, 0, stream>>>(qkvb, Vt, biasa, ctxb);
  // sum1 = ctx @ Wo^T + bo + src   (fp32)
  gemm_nt<false><<<dim3(1024 / 128, 4096 / 128), 256, 0, stream>>>(
      ctxb, Wob, bo, src, sum1, nullptr, 4096, 1024, 1024);
  // x = LN(sum1) -> xf fp32 + xb bf16
  ln_kernel<<<4096, 256, 0, stream>>>(sum1, g1, b1n, xf, xb);
  // h = gelu(x @ W1^T + b1) -> bf16 [4096, 4096]
  gemm_nt<true><<<dim3(4096 / 128, 4096 / 128), 256, 0, stream>>>(
      xb, W1b, b1, nullptr, nullptr, hb, 4096, 4096, 1024);
  // y = h @ W2^T + b2 + x   (fp32)
  gemm_nt<false><<<dim3(1024 / 128, 4096 / 128), 256, 0, stream>>>(
      hb, W2b, b2, xf, yf, nullptr, 4096, 1024, 4096);
  // out = LN(y)
  ln_kernel<<<4096, 256, 0, stream>>>(yf, g2, b2n, out, nullptr);
}

// Round 7
// 398.665 us; speedup vs baseline: 1.0700x; 1.0700x over previous
//
#include <hip/hip_runtime.h>
#include <cstdint>

typedef unsigned short u16;
typedef __bf16 bf16x8 __attribute__((ext_vector_type(8)));
typedef float f32x4 __attribute__((ext_vector_type(4)));
typedef unsigned short u16x8 __attribute__((ext_vector_type(8)));
typedef unsigned short u16x4 __attribute__((ext_vector_type(4)));

// ---------- helpers ----------
__device__ __forceinline__ u16 f2b(float f) {  // fp32 -> bf16 RNE
  union { float f; unsigned u; } x; x.f = f;
  unsigned r = (x.u + 0x7FFFu + ((x.u >> 16) & 1u)) >> 16;
  return (u16)r;
}
__device__ __forceinline__ float b2f(u16 v) {
  union { unsigned u; float f; } x; x.u = (unsigned)v << 16; return x.f;
}

__device__ __forceinline__ void gload_lds16(const void* g, void* l) {
  __builtin_amdgcn_global_load_lds(
      (__attribute__((address_space(1))) void*)(uintptr_t)g,
      (__attribute__((address_space(3))) void*)(uintptr_t)l, 16, 0, 0);
}

// ---------- fp32 -> bf16 cast ----------
__global__ void cast_kernel(const float* __restrict__ in, u16* __restrict__ out, int n4) {
  int i = blockIdx.x * 256 + threadIdx.x;
  if (i < n4) {
    float4 v = *(const float4*)(in + (size_t)i * 4);
    u16x4 o = {f2b(v.x), f2b(v.y), f2b(v.z), f2b(v.w)};
    *(u16x4*)(out + (size_t)i * 4) = o;
  }
}

// ---------- GEMM: C[M,N] = A[M,K] * B[N,K]^T (+bias, +gelu, +resid) ----------
template<bool GELU_ACT>
__global__ void gemm_nt(const u16* __restrict__ A, const u16* __restrict__ Bw,
                        const float* __restrict__ bias, const float* __restrict__ resid,
                        float* __restrict__ Cf, u16* __restrict__ Cb,
                        int M, int N, int K) {
  __shared__ u16 As[2][128 * 32];
  __shared__ u16 Bs[2][128 * 32];
  const int tid = threadIdx.x;
  const int lane = tid & 63, wid = tid >> 6;
  const int bm = blockIdx.y * 128, bn = blockIdx.x * 128;
  const int wm = wid >> 1, wn = wid & 1;
  const int r = lane & 15, g = lane >> 4;

  auto stage = [&](int buf, int k0) {
#pragma unroll
    for (int i = 0; i < 2; ++i) {
      int c = tid + i * 256;
      const u16* ga = A + (size_t)(bm + (c >> 2)) * K + k0 + (c & 3) * 8;
      const u16* gb = Bw + (size_t)(bn + (c >> 2)) * K + k0 + (c & 3) * 8;
      gload_lds16(ga, &As[buf][c * 8]);
      gload_lds16(gb, &Bs[buf][c * 8]);
    }
  };

  f32x4 acc[4][4] = {};
  stage(0, 0);
  __syncthreads();
  const int nk = K >> 5;
  int cur = 0;
  for (int kt = 0; kt < nk; ++kt) {
    if (kt + 1 < nk) stage(cur ^ 1, (kt + 1) * 32);
    bf16x8 af[4], bfr[4];
#pragma unroll
    for (int m = 0; m < 4; ++m)
      af[m] = *(const bf16x8*)&As[cur][(wm * 64 + m * 16 + r) * 32 + g * 8];
#pragma unroll
    for (int n = 0; n < 4; ++n)
      bfr[n] = *(const bf16x8*)&Bs[cur][(wn * 64 + n * 16 + r) * 32 + g * 8];
#pragma unroll
    for (int m = 0; m < 4; ++m)
#pragma unroll
      for (int n = 0; n < 4; ++n)
        acc[m][n] = __builtin_amdgcn_mfma_f32_16x16x32_bf16(af[m], bfr[n], acc[m][n], 0, 0, 0);
    __syncthreads();
    cur ^= 1;
  }
#pragma unroll
  for (int m = 0; m < 4; ++m) {
    const int row0 = bm + wm * 64 + m * 16 + g * 4;
#pragma unroll
    for (int n = 0; n < 4; ++n) {
      const int col = bn + wn * 64 + n * 16 + r;
      const float bv = bias ? bias[col] : 0.f;
#pragma unroll
      for (int j = 0; j < 4; ++j) {
        float v = acc[m][n][j] + bv;
        if (GELU_ACT) v = 0.5f * v * (1.f + erff(v * 0.70710678118654752f));
        const size_t idx = (size_t)(row0 + j) * N + col;
        if (resid) v += resid[idx];
        if (Cf) Cf[idx] = v;
        if (Cb) Cb[idx] = f2b(v);
      }
    }
  }
}

// ---------- V transpose: qkv[4096,3072] -> Vt[64 bh][64 d][1024 s] ----------
__global__ void vtrans_kernel(const u16* __restrict__ qkv, u16* __restrict__ Vt) {
  const int bh = blockIdx.y, b = bh >> 4, h = bh & 15;
  const int s0 = blockIdx.x * 128;
  const int tid = threadIdx.x;
  __shared__ u16 t[128][66];
#pragma unroll
  for (int i = 0; i < 32; ++i) {
    const int e = tid + i * 256;
    const int s = e >> 6, d = e & 63;
    t[s][d] = qkv[(size_t)(b * 1024 + s0 + s) * 3072 + 2048 + h * 64 + d];
  }
  __syncthreads();
#pragma unroll
  for (int i = 0; i < 4; ++i) {
    const int c = tid + i * 256;
    const int d = c >> 4, scol = (c & 15) * 8;
    u16x8 v;
#pragma unroll
    for (int j = 0; j < 8; ++j) v[j] = t[scol + j][d];
    *(u16x8*)(Vt + ((size_t)bh * 64 + d) * 1024 + s0 + scol) = v;
  }
}

// ---------- fused attention v7 ----------
// Pass A: swapped-operand QK^T (mfma(K,Q)) -> lane holds 4 CONSECUTIVE keys
// of one q-row -> single ds_write_b64 per tile (16 total; no scalar RMW).
// Pass B: per-row vectorized softmax (v5) + bias added from global bf16 in
// natural layout. P normalized in place. Pass C: PV, dual accumulators.
// Two barriers, zero cross-wave reductions, (row&15)<<3 swizzle (0-conflict).
__global__ __launch_bounds__(256) void attn_kernel(
    const u16* __restrict__ qkv, const u16* __restrict__ Vt,
    const u16* __restrict__ biasb, u16* __restrict__ ctx) {
  const int yy = blockIdx.y;           // h*4 + b
  const int h = yy >> 2, b = yy & 3;
  const int q0 = blockIdx.x * 16;
  const int tid = threadIdx.x;
  const int lane = tid & 63, wid = tid >> 6;
  const int r = lane & 15, g = lane >> 4;
  const int bh = b * 16 + h;

  __shared__ __align__(16) u16 PB[16 * 1024];

  // Q fragments: row = lane&15 (q-row), k = g*8..
  const size_t qbase = (size_t)(b * 1024 + q0 + r) * 3072 + h * 64;
  const bf16x8 aq0 = *(const bf16x8*)(qkv + qbase + g * 8);
  const bf16x8 aq1 = *(const bf16x8*)(qkv + qbase + 32 + g * 8);

  const int n0 = wid * 256;            // this wave's 256 key columns

  // pass A: S tile via mfma(K,Q): lane (r,g) holds S[q=r][key=nt*16+g*4+j]
#pragma unroll 4
  for (int nt = 0; nt < 16; ++nt) {
    const int key = n0 + nt * 16 + r;  // K-frag row = key
    const size_t kbase = (size_t)(b * 1024 + key) * 3072 + 1024 + h * 64;
    const bf16x8 bk0 = *(const bf16x8*)(qkv + kbase + g * 8);
    const bf16x8 bk1 = *(const bf16x8*)(qkv + kbase + 32 + g * 8);
    f32x4 a = {0.f, 0.f, 0.f, 0.f};
    a = __builtin_amdgcn_mfma_f32_16x16x32_bf16(bk0, aq0, a, 0, 0, 0);
    a = __builtin_amdgcn_mfma_f32_16x16x32_bf16(bk1, aq1, a, 0, 0, 0);
    u16x4 o = {f2b(a[0] * 0.125f), f2b(a[1] * 0.125f),
               f2b(a[2] * 0.125f), f2b(a[3] * 0.125f)};
    const int col = n0 + nt * 16 + g * 4;
    *(u16x4*)&PB[r * 1024 + (col ^ ((r & 15) << 3))] = o;
  }
  __syncthreads();                     // all scores in LDS

  // pass B: wave owns rows wid*4..+3; lane slices 16 cols; bias from global
  const u16* bbase = biasb + ((size_t)h * 1024 + q0) * 1024;
#pragma unroll
  for (int rr = 0; rr < 4; ++rr) {
    const int row = wid * 4 + rr;
    const int swz = (row & 15) << 3;
    u16* prow = &PB[row * 1024];
    const int c0 = lane * 16;
    const u16x8 b0 = *(const u16x8*)(bbase + (size_t)row * 1024 + c0);
    const u16x8 b1 = *(const u16x8*)(bbase + (size_t)row * 1024 + c0 + 8);
    const u16x8 v0 = *(const u16x8*)&prow[c0 ^ swz];
    const u16x8 v1 = *(const u16x8*)&prow[(c0 + 8) ^ swz];
    float f[16];
#pragma unroll
    for (int k = 0; k < 8; ++k) {
      f[k]     = b2f(v0[k]) + b2f(b0[k]);
      f[8 + k] = b2f(v1[k]) + b2f(b1[k]);
    }
    float m = f[0];
#pragma unroll
    for (int k = 1; k < 16; ++k) m = fmaxf(m, f[k]);
    m = fmaxf(m, __shfl_xor(m, 1));  m = fmaxf(m, __shfl_xor(m, 2));
    m = fmaxf(m, __shfl_xor(m, 4));  m = fmaxf(m, __shfl_xor(m, 8));
    m = fmaxf(m, __shfl_xor(m, 16)); m = fmaxf(m, __shfl_xor(m, 32));
    float s = 0.f;
#pragma unroll
    for (int k = 0; k < 16; ++k) { f[k] = __expf(f[k] - m); s += f[k]; }
    s += __shfl_xor(s, 1);  s += __shfl_xor(s, 2);
    s += __shfl_xor(s, 4);  s += __shfl_xor(s, 8);
    s += __shfl_xor(s, 16); s += __shfl_xor(s, 32);
    const float inv = 1.f / s;
    u16x8 o0, o1;
#pragma unroll
    for (int k = 0; k < 8; ++k) {
      o0[k] = f2b(f[k] * inv);
      o1[k] = f2b(f[8 + k] * inv);
    }
    *(u16x8*)&prow[c0 ^ swz] = o0;
    *(u16x8*)&prow[(c0 + 8) ^ swz] = o1;
  }
  __syncthreads();                     // normalized P ready

  // pass C (PV): wave wid owns d-tile [wid*16, wid*16+16); 2 indep chains
  f32x4 oa = {0.f, 0.f, 0.f, 0.f}, ob = {0.f, 0.f, 0.f, 0.f};
  const u16* vrow = Vt + ((size_t)bh * 64 + wid * 16 + r) * 1024;
#pragma unroll 4
  for (int ks = 0; ks < 32; ks += 2) {
    const bf16x8 pa0 = *(const bf16x8*)&PB[r * 1024 + ((ks * 32 + g * 8) ^ ((r & 15) << 3))];
    const bf16x8 vb0 = *(const bf16x8*)(vrow + ks * 32 + g * 8);
    oa = __builtin_amdgcn_mfma_f32_16x16x32_bf16(pa0, vb0, oa, 0, 0, 0);
    const bf16x8 pa1 = *(const bf16x8*)&PB[r * 1024 + (((ks + 1) * 32 + g * 8) ^ ((r & 15) << 3))];
    const bf16x8 vb1 = *(const bf16x8*)(vrow + (ks + 1) * 32 + g * 8);
    ob = __builtin_amdgcn_mfma_f32_16x16x32_bf16(pa1, vb1, ob, 0, 0, 0);
  }
#pragma unroll
  for (int j = 0; j < 4; ++j)
    ctx[(size_t)(b * 1024 + q0 + g * 4 + j) * 1024 + h * 64 + wid * 16 + r] =
        f2b(oa[j] + ob[j]);
}

// ---------- LayerNorm over D=1024, one block per row ----------
__global__ void ln_kernel(const float* __restrict__ x, const float* __restrict__ gw,
                          const float* __restrict__ bw, float* __restrict__ outf,
                          u16* __restrict__ outb) {
  const int row = blockIdx.x, tid = threadIdx.x;
  const float4 v = *(const float4*)(x + (size_t)row * 1024 + tid * 4);
  float s = v.x + v.y + v.z + v.w;
  float q = v.x * v.x + v.y * v.y + v.z * v.z + v.w * v.w;
#pragma unroll
  for (int m = 32; m >= 1; m >>= 1) { s += __shfl_xor(s, m); q += __shfl_xor(q, m); }
  __shared__ float rs[4], rq[4];
  if ((tid & 63) == 0) { rs[tid >> 6] = s; rq[tid >> 6] = q; }
  __syncthreads();
  s = rs[0] + rs[1] + rs[2] + rs[3];
  q = rq[0] + rq[1] + rq[2] + rq[3];
  const float mu = s * (1.f / 1024.f);
  const float inv = rsqrtf(q * (1.f / 1024.f) - mu * mu + 1e-5f);
  const float4 g4 = *(const float4*)(gw + tid * 4);
  const float4 b4 = *(const float4*)(bw + tid * 4);
  float4 o;
  o.x = (v.x - mu) * inv * g4.x + b4.x;
  o.y = (v.y - mu) * inv * g4.y + b4.y;
  o.z = (v.z - mu) * inv * g4.z + b4.z;
  o.w = (v.w - mu) * inv * g4.w + b4.w;
  if (outf) *(float4*)(outf + (size_t)row * 1024 + tid * 4) = o;
  if (outb) {
    u16x4 ob = {f2b(o.x), f2b(o.y), f2b(o.z), f2b(o.w)};
    *(u16x4*)(outb + (size_t)row * 1024 + tid * 4) = ob;
  }
}

// ---------- launch ----------
extern "C" void kernel_launch(void* const* d_in, const int* in_sizes, int n_in,
                              void* d_out, int out_size, void* d_ws, size_t ws_size,
                              hipStream_t stream) {
  (void)in_sizes; (void)n_in; (void)out_size; (void)ws_size;
  const float* src   = (const float*)d_in[0];
  const float* abias = (const float*)d_in[1];
  const float* Wqkv  = (const float*)d_in[2];
  const float* bqkv  = (const float*)d_in[3];
  const float* Wo    = (const float*)d_in[4];
  const float* bo    = (const float*)d_in[5];
  const float* g1    = (const float*)d_in[6];
  const float* b1n   = (const float*)d_in[7];
  const float* g2    = (const float*)d_in[8];
  const float* b2n   = (const float*)d_in[9];
  const float* W1    = (const float*)d_in[10];
  const float* b1    = (const float*)d_in[11];
  const float* W2    = (const float*)d_in[12];
  const float* b2    = (const float*)d_in[13];
  float* out = (float*)d_out;

  char* ws = (char*)d_ws;
  const size_t MB = 1024 * 1024;
  // lifetime-aliased layout, 104 MB total
  u16* srcb  = (u16*)(ws + 0 * MB);     // dead after gemm1
  u16* ctxb  = (u16*)(ws + 0 * MB);     // alias of srcb (written by attn)
  u16* Wqkvb = (u16*)(ws + 8 * MB);
  u16* Wob   = (u16*)(ws + 14 * MB);
  u16* W1b   = (u16*)(ws + 16 * MB);
  u16* W2b   = (u16*)(ws + 24 * MB);
  u16* qkvb  = (u16*)(ws + 32 * MB);    // 24 MB; dead after attn
  u16* hb    = (u16*)(ws + 32 * MB);    // alias (32 MB, written by gemm3)
  u16* Vt    = (u16*)(ws + 56 * MB);    // 8 MB; dead after attn
  u16* biasb = (u16*)(ws + 64 * MB);    // 32 MB (64..96); dead after attn
  float* sum1 = (float*)(ws + 64 * MB); // 16 MB (after attn); dead after ln1
  float* yf   = (float*)(ws + 64 * MB); // alias (written by gemm4)
  float* xf   = (float*)(ws + 80 * MB); // written by ln1 (after attn)
  u16* xb    = (u16*)(ws + 96 * MB);

  auto cast = [&](const float* in, u16* o, int n) {
    cast_kernel<<<(n / 4 + 255) / 256, 256, 0, stream>>>(in, o, n / 4);
  };
  cast(src, srcb, 4096 * 1024);
  cast(Wqkv, Wqkvb, 3072 * 1024);
  cast(Wo, Wob, 1024 * 1024);
  cast(W1, W1b, 4096 * 1024);
  cast(W2, W2b, 1024 * 4096);
  cast(abias, biasb, 16 * 1024 * 1024);  // bias: plain bf16, natural layout

  // qkv = src @ Wqkv^T + bqkv  -> bf16 [4096, 3072]
  gemm_nt<false><<<dim3(3072 / 128, 4096 / 128), 256, 0, stream>>>(
      srcb, Wqkvb, bqkv, nullptr, nullptr, qkvb, 4096, 3072, 1024);
  // Vt[bh][d][s]
  vtrans_kernel<<<dim3(8, 64), 256, 0, stream>>>(qkvb, Vt);
  // attention -> ctx bf16 [4096, 1024]
  attn_kernel<<<dim3(64, 64), 256, 0, stream>>>(qkvb, Vt, biasb, ctxb);
  // sum1 = ctx @ Wo^T + bo + src   (fp32)
  gemm_nt<false><<<dim3(1024 / 128, 4096 / 128), 256, 0, stream>>>(
      ctxb, Wob, bo, src, sum1, nullptr, 4096, 1024, 1024);
  // x = LN(sum1) -> xf fp32 + xb bf16
  ln_kernel<<<4096, 256, 0, stream>>>(sum1, g1, b1n, xf, xb);
  // h = gelu(x @ W1^T + b1) -> bf16 [4096, 4096]
  gemm_nt<true><<<dim3(4096 / 128, 4096 / 128), 256, 0, stream>>>(
      xb, W1b, b1, nullptr, nullptr, hb, 4096, 4096, 1024);
  // y = h @ W2^T + b2 + x   (fp32)
  gemm_nt<false><<<dim3(1024 / 128, 4096 / 128), 256, 0, stream>>>(
      hb, W2b, b2, xf, yf, nullptr, 4096, 1024, 4096);
  // out = LN(y)
  ln_kernel<<<4096, 256, 0, stream>>>(yf, g2, b2n, out, nullptr);
}